// Round 9
// baseline (174.164 us; speedup 1.0000x reference)
//
#include <hip/hip_runtime.h>
#include <hip/hip_bf16.h>

// ---- types ----
typedef short bf16x8 __attribute__((ext_vector_type(8)));          // 8 bf16 = 4 VGPRs (MFMA A/B frag)
typedef unsigned short u16x8 __attribute__((ext_vector_type(8)));
typedef unsigned short u16x4 __attribute__((ext_vector_type(4)));
typedef float f32x4 __attribute__((ext_vector_type(4)));           // MFMA C/D frag

typedef unsigned int __attribute__((address_space(1))) gu32;       // global
typedef unsigned int __attribute__((address_space(3))) lu32;       // LDS

#define MFMA16(a, b, c) __builtin_amdgcn_mfma_f32_16x16x32_bf16((a), (b), (c), 0, 0, 0)

constexpr int SEQ = 2048;
constexpr int NH = 16;
constexpr int NTOK = 2 * SEQ;  // 4096

__device__ __forceinline__ float bf2f(unsigned short u) {
  union { unsigned int i; float f; } v; v.i = ((unsigned int)u) << 16; return v.f;
}
__device__ __forceinline__ unsigned short f2bf(float f) {
  __hip_bfloat16 h = __float2bfloat16(f);   // RNE
  return __builtin_bit_cast(unsigned short, h);
}
// pack two fp32 -> bf16 pair by TRUNCATION via one v_perm_b32 (hi<<16 | lo)
__device__ __forceinline__ unsigned int pkbf_trunc(float hi, float lo) {
  return __builtin_amdgcn_perm(__builtin_bit_cast(unsigned int, hi),
                               __builtin_bit_cast(unsigned int, lo), 0x07060302u);
}
__device__ __forceinline__ u16x8 cvt8(const float* __restrict__ p) {
  f32x4 a = *(const f32x4*)p;
  f32x4 b = *(const f32x4*)(p + 4);
  u16x8 r;
#pragma unroll
  for (int j = 0; j < 4; j++) { r[j] = f2bf(a[j]); r[4 + j] = f2bf(b[j]); }
  return r;
}

// =====================================================================
// Convert pass: x (4M) and Wq/Wk/Wv/Wo (1M each) fp32 -> bf16 into ws.
// (~13 µs, at its 72 MB memory roofline — frozen)
// =====================================================================
__global__ __launch_bounds__(256) void cvt_all(
    const float* __restrict__ x, const float* __restrict__ wq, const float* __restrict__ wk,
    const float* __restrict__ wv, const float* __restrict__ wo,
    unsigned short* __restrict__ Xb, unsigned short* __restrict__ Wb) {
  const int z = blockIdx.y;
  const float* src = (z == 0) ? x : (z == 1) ? wq : (z == 2) ? wk : (z == 3) ? wv : wo;
  unsigned short* dst = (z == 0) ? Xb : Wb + (size_t)(z - 1) * 1024 * 1024;
  const int n = (z == 0) ? NTOK * 1024 : 1024 * 1024;
  for (int i = (blockIdx.x * 256 + threadIdx.x) * 8; i < n; i += gridDim.x * 256 * 8)
    *(u16x8*)(dst + i) = cvt8(src + i);
}

// =====================================================================
// Async global->LDS staging with XOR-chunk permutation (verified r3):
// 16B chunk (row, c8) -> slot row*8 + (c8 ^ (row&7)).
// =====================================================================
template <int ROWS, int NWAVE>
__device__ __forceinline__ void stage_glds(const unsigned short* __restrict__ gbase,
                                           int rstride,
                                           unsigned short* __restrict__ lds,
                                           int wid, int lane) {
  constexpr int ISS = ROWS * 8 / (NWAVE * 64);
#pragma unroll
  for (int t = 0; t < ISS; ++t) {
    const int slot = (wid * ISS + t) * 64 + lane;
    const int row = slot >> 3;
    const int c8 = (slot & 7) ^ (row & 7);
    const unsigned short* gp = gbase + (size_t)row * rstride + c8 * 8;
    unsigned short* lp = lds + (size_t)(wid * ISS + t) * 512;   // wave-uniform, 1 KiB/issue
    __builtin_amdgcn_global_load_lds((const gu32*)gp, (lu32*)lp, 16, 0, 0);
  }
}

__device__ __forceinline__ bf16x8 frag_ld(const unsigned short* __restrict__ lds, int row, int c8) {
  const int slot = row * 8 + (c8 ^ (row & 7));
  return *(const bf16x8*)(lds + slot * 8);
}

#define SBAR do { __builtin_amdgcn_sched_barrier(0); \
                  asm volatile("s_barrier" ::: "memory"); \
                  __builtin_amdgcn_sched_barrier(0); } while (0)

// =====================================================================
// QKV projection: 256x192-tile 8-phase GEMM (T2+T3+T4+T5) — verified
// r5/r8 (256 blocks = 100% CU, one barrier/phase). vmcnt(3) at P4/P8.
// =====================================================================
__global__ __launch_bounds__(512) void gemm_8ph_w192(
    const unsigned short* __restrict__ A,   // [4096][1024] bf16
    const unsigned short* __restrict__ B,   // [3072][1024] bf16 (Wq|Wk|Wv rows)
    unsigned short* __restrict__ C) {       // [4096][3072] bf16
  constexpr int K = 1024;
  __shared__ __align__(16) unsigned short As[2][256 * 64];   // 32 KiB x2
  __shared__ __align__(16) unsigned short Bs[2][192 * 64];   // 24 KiB x2

  const int tid = threadIdx.x;
  const int wid = tid >> 6, lane = tid & 63;
  const int quad = lane >> 4, c16 = lane & 15;
  const int wr = wid >> 2;        // 0..1  -> 128 output rows
  const int wc = wid & 3;         // 0..3  -> 48 output cols

  const int bid = blockIdx.x;
  const int swz = (bid & 7) * 32 + (bid >> 3);
  const int m0 = (swz >> 4) * 256;
  const int n0 = (swz & 15) * 192;

  const unsigned short* Abase = A + (size_t)m0 * K;
  const unsigned short* Bbase = B + (size_t)n0 * K;

  f32x4 acc[8][3];
#pragma unroll
  for (int i = 0; i < 8; i++)
#pragma unroll
    for (int j = 0; j < 3; j++) acc[i][j] = f32x4{0.f, 0.f, 0.f, 0.f};

  bf16x8 af[4];
  bf16x8 bf0[3];
  bf16x8 bf1[3];

  auto lda4 = [&](const unsigned short* asb, int mo, int ks) {
#pragma unroll
    for (int mi = 0; mi < 4; mi++)
      af[mi] = frag_ld(asb, wr * 128 + (mo + mi) * 16 + c16, ks * 4 + quad);
  };
  auto ldb3 = [&](const unsigned short* bsb, bf16x8 (&bf)[3], int ks) {
#pragma unroll
    for (int ni = 0; ni < 3; ni++)
      bf[ni] = frag_ld(bsb, wc * 48 + ni * 16 + c16, ks * 4 + quad);
  };
  auto mm12 = [&](bf16x8 (&bf)[3], int mo) {
    __builtin_amdgcn_s_setprio(1);
#pragma unroll
    for (int mi = 0; mi < 4; mi++)
#pragma unroll
      for (int ni = 0; ni < 3; ni++)
        acc[mo + mi][ni] = MFMA16(af[mi], bf[ni], acc[mo + mi][ni]);
    __builtin_amdgcn_s_setprio(0);
  };

  // ---- prologue
  stage_glds<192, 8>(Bbase, K, Bs[0], wid, lane);
  stage_glds<128, 8>(Abase, K, As[0], wid, lane);
  stage_glds<128, 8>(Abase + (size_t)128 * K, K, As[0] + 8192, wid, lane);
  stage_glds<192, 8>(Bbase + 64, K, Bs[1], wid, lane);
  asm volatile("s_waitcnt vmcnt(3)" ::: "memory");   // tile 0 landed; B(1) in flight
  SBAR;

  for (int i = 0; i < 7; ++i) {
    const int t = 2 * i;
    const int kb1 = (t + 1) * 64, kb2 = (t + 2) * 64, kb3 = (t + 3) * 64;
    // P1
    lda4(As[0], 0, 0); ldb3(Bs[0], bf0, 0);
    stage_glds<128, 8>(Abase + kb1, K, As[1], wid, lane);
    mm12(bf0, 0); SBAR;
    // P2
    lda4(As[0], 0, 1); ldb3(Bs[0], bf1, 1);
    stage_glds<128, 8>(Abase + (size_t)128 * K + kb1, K, As[1] + 8192, wid, lane);
    mm12(bf1, 0); SBAR;
    // P3
    lda4(As[0], 4, 0);
    stage_glds<192, 8>(Bbase + kb2, K, Bs[0], wid, lane);
    mm12(bf0, 4); SBAR;
    // P4
    lda4(As[0], 4, 1);
    asm volatile("s_waitcnt vmcnt(3)" ::: "memory");   // t+1 landed; B(t+2) in flight
    mm12(bf1, 4); SBAR;
    // P5
    lda4(As[1], 0, 0); ldb3(Bs[1], bf0, 0);
    stage_glds<128, 8>(Abase + kb2, K, As[0], wid, lane);
    mm12(bf0, 0); SBAR;
    // P6
    lda4(As[1], 0, 1); ldb3(Bs[1], bf1, 1);
    stage_glds<128, 8>(Abase + (size_t)128 * K + kb2, K, As[0] + 8192, wid, lane);
    mm12(bf1, 0); SBAR;
    // P7
    lda4(As[1], 4, 0);
    stage_glds<192, 8>(Bbase + kb3, K, Bs[1], wid, lane);
    mm12(bf0, 4); SBAR;
    // P8
    lda4(As[1], 4, 1);
    asm volatile("s_waitcnt vmcnt(3)" ::: "memory");   // t+2 landed; B(t+3) in flight
    mm12(bf1, 4); SBAR;
  }

  // ---- final iteration: t=14 (buf0), t=15 (buf1); stage only A(15)
  {
    const int kb1 = 15 * 64;
    lda4(As[0], 0, 0); ldb3(Bs[0], bf0, 0);
    stage_glds<128, 8>(Abase + kb1, K, As[1], wid, lane);
    mm12(bf0, 0); SBAR;
    lda4(As[0], 0, 1); ldb3(Bs[0], bf1, 1);
    stage_glds<128, 8>(Abase + (size_t)128 * K + kb1, K, As[1] + 8192, wid, lane);
    mm12(bf1, 0); SBAR;
    lda4(As[0], 4, 0);
    mm12(bf0, 4); SBAR;
    lda4(As[0], 4, 1);
    asm volatile("s_waitcnt vmcnt(0)" ::: "memory");   // drain: A(15) covered
    mm12(bf1, 4); SBAR;
    lda4(As[1], 0, 0); ldb3(Bs[1], bf0, 0);
    mm12(bf0, 0); SBAR;
    lda4(As[1], 0, 1); ldb3(Bs[1], bf1, 1);
    mm12(bf1, 0); SBAR;
    lda4(As[1], 4, 0);
    mm12(bf0, 4); SBAR;
    lda4(As[1], 4, 1);
    mm12(bf1, 4);
  }

#pragma unroll
  for (int mi = 0; mi < 8; mi++) {
#pragma unroll
    for (int ni = 0; ni < 3; ni++) {
      const int row = m0 + wr * 128 + mi * 16 + quad * 4;
      const int col = n0 + wc * 48 + ni * 16 + c16;
#pragma unroll
      for (int r = 0; r < 4; r++)
        C[(size_t)(row + r) * 3072 + col] = f2bf(acc[mi][ni][r]);
    }
  }
}

// =====================================================================
// NEW: output projection as 128x64-tile, 4-wave, double-buffered,
// counted-vmcnt GEMM (transplant of the audited w192 schedule).
// Old gemm_lds did sync->stage->sync(full vmcnt0 drain)->compute per
// K-tile = 16 exposed HBM latencies/block. New: pair iteration
// (tiles t,t+1), 4 phases, 1 barrier each; stages Ph1:A(t+1)->As1,
// Ph2:B(t+2)->Bs0, Ph3:A(t+2)->As0, Ph4:B(t+3)->Bs1.
// Issue-order wait audit: entering Ph1 outstanding=B(t+1):2;
// Ph2 end: +A(t+1):4 +B(t+2):2 =8 -> vmcnt(2) retires A(t+1),B(t+1)
// (read in Ph3/Ph4), leaves B(t+2). Ph4 end: B(t+2):2+A(t+2):4+
// B(t+3):2 =8 -> vmcnt(2) retires tile t+2 (read next Ph1), leaves
// B(t+3). Final pair: vmcnt(0) at Ph2 (covers A(15)). LDS 48 KB,
// grid 512 (2/CU grid-capped), n-fastest XCD swizzle (4 A-panels=1MB
// L2-resident per XCD).
// =====================================================================
__global__ __launch_bounds__(256) void gemm_op_2ph(
    const unsigned short* __restrict__ A,   // [4096][1024] bf16 (attn out)
    const unsigned short* __restrict__ B,   // [1024][1024] bf16 (Wo rows)
    float* __restrict__ C) {                // [4096][1024] fp32
  constexpr int K = 1024;
  __shared__ __align__(16) unsigned short As[2][128 * 64];   // 16 KiB x2
  __shared__ __align__(16) unsigned short Bs[2][64 * 64];    // 8 KiB x2

  const int tid = threadIdx.x;
  const int wid = tid >> 6, lane = tid & 63;
  const int quad = lane >> 4, c16 = lane & 15;
  const int wr = wid >> 1, wc = wid & 1;   // wave-tile 64x32

  const int bid = blockIdx.x;
  const int swz = (bid & 7) * 64 + (bid >> 3);   // 512 % 8 == 0: bijective
  const int m0 = (swz >> 4) * 128;               // n fastest within XCD
  const int n0 = (swz & 15) * 64;

  const unsigned short* Abase = A + (size_t)m0 * K;
  const unsigned short* Bbase = B + (size_t)n0 * K;

  f32x4 acc[4][2];
#pragma unroll
  for (int i = 0; i < 4; i++)
#pragma unroll
    for (int j = 0; j < 2; j++) acc[i][j] = f32x4{0.f, 0.f, 0.f, 0.f};

  bf16x8 af[2][2];   // 2 m-rows x 2 ks
  bf16x8 bf[2][2];   // 2 n-cols x 2 ks (live across the two phases of a tile)

  auto lda22 = [&](const unsigned short* asb, int mo) {
#pragma unroll
    for (int mi = 0; mi < 2; mi++)
#pragma unroll
      for (int ks = 0; ks < 2; ks++)
        af[mi][ks] = frag_ld(asb, wr * 64 + (mo + mi) * 16 + c16, ks * 4 + quad);
  };
  auto ldb22 = [&](const unsigned short* bsb) {
#pragma unroll
    for (int ni = 0; ni < 2; ni++)
#pragma unroll
      for (int ks = 0; ks < 2; ks++)
        bf[ni][ks] = frag_ld(bsb, wc * 32 + ni * 16 + c16, ks * 4 + quad);
  };
  auto mm8 = [&](int mo) {
    __builtin_amdgcn_s_setprio(1);
#pragma unroll
    for (int mi = 0; mi < 2; mi++)
#pragma unroll
      for (int ni = 0; ni < 2; ni++)
#pragma unroll
        for (int ks = 0; ks < 2; ks++)
          acc[mo + mi][ni] = MFMA16(af[mi][ks], bf[ni][ks], acc[mo + mi][ni]);
    __builtin_amdgcn_s_setprio(0);
  };

  // ---- prologue: B(0)[2], A(0)[4], B(1)[2] -> vmcnt(2): tile 0 landed
  stage_glds<64, 4>(Bbase, K, Bs[0], wid, lane);
  stage_glds<128, 4>(Abase, K, As[0], wid, lane);
  stage_glds<64, 4>(Bbase + 64, K, Bs[1], wid, lane);
  asm volatile("s_waitcnt vmcnt(2)" ::: "memory");
  SBAR;

  for (int i = 0; i < 7; ++i) {
    const int t = 2 * i;
    const int kb1 = (t + 1) * 64, kb2 = (t + 2) * 64, kb3 = (t + 3) * 64;
    // Ph1: read t mo01 (A+B); stage A(t+1)->As1
    lda22(As[0], 0); ldb22(Bs[0]);
    stage_glds<128, 4>(Abase + kb1, K, As[1], wid, lane);
    mm8(0); SBAR;
    // Ph2: read t mo23; stage B(t+2)->Bs0; vmcnt(2) -> t+1 landed
    lda22(As[0], 2);
    stage_glds<64, 4>(Bbase + kb2, K, Bs[0], wid, lane);
    asm volatile("s_waitcnt vmcnt(2)" ::: "memory");
    mm8(2); SBAR;
    // Ph3: read t+1 mo01 (A+B); stage A(t+2)->As0
    lda22(As[1], 0); ldb22(Bs[1]);
    stage_glds<128, 4>(Abase + kb2, K, As[0], wid, lane);
    mm8(0); SBAR;
    // Ph4: read t+1 mo23; stage B(t+3)->Bs1; vmcnt(2) -> t+2 landed
    lda22(As[1], 2);
    stage_glds<64, 4>(Bbase + kb3, K, Bs[1], wid, lane);
    asm volatile("s_waitcnt vmcnt(2)" ::: "memory");
    mm8(2); SBAR;
  }

  // ---- final pair: t=14 (buf0), t=15 (buf1); stage only A(15)
  {
    const int kb1 = 15 * 64;
    lda22(As[0], 0); ldb22(Bs[0]);
    stage_glds<128, 4>(Abase + kb1, K, As[1], wid, lane);
    mm8(0); SBAR;
    lda22(As[0], 2);
    asm volatile("s_waitcnt vmcnt(0)" ::: "memory");   // A(15)+B(15) landed
    mm8(2); SBAR;
    lda22(As[1], 0); ldb22(Bs[1]);
    mm8(0); SBAR;
    lda22(As[1], 2);
    mm8(2);
  }

  // ---- epilogue: fp32 C, same per-fragment mapping as verified kernels
#pragma unroll
  for (int a = 0; a < 4; a++) {
#pragma unroll
    for (int ni = 0; ni < 2; ni++) {
      const int row = m0 + wr * 64 + a * 16 + quad * 4;
      const int col = n0 + wc * 32 + ni * 16 + c16;
#pragma unroll
      for (int r = 0; r < 4; r++)
        C[(size_t)(row + r) * 1024 + col] = acc[a][ni][r];
    }
  }
}

// =====================================================================
// Flash attention v14 (causal) — single-barrier pipeline, Vt dbuf
// (verified r7/r8: 41.3 µs). At its structural floor for this
// decomposition (r8 bank-audit: all LDS accesses balanced). FROZEN.
// =====================================================================
__device__ __forceinline__ int vt_idx(int d, int kv) {
  int ck = kv >> 3;
  int s = ((d >> 3) ^ d) & 7;
  return d * 64 + ((ck ^ s) << 3) + (kv & 7);
}

struct AttnShared {
  unsigned short Kt[2][64 * 64];   // XOR-chunk swizzled K rows (8 KB x2)
  unsigned short Vt[2][64 * 64];   // vt_idx-swizzled V^T (8 KB x2)
  unsigned short Pt[4][16 * 64];   // per-wave 16x64 XOR-chunk P^T tile (8 KB)
};

__global__ __launch_bounds__(256) void attn_kernel(
    const unsigned short* __restrict__ QKV,   // [NTOK][3072]: Q | K | V (bf16)
    unsigned short* __restrict__ Oa) {        // [NTOK][1024] bf16
  __shared__ AttnShared sh;
  const int h = blockIdx.x;
  const int b = blockIdx.y;
  const int t = 31 - blockIdx.z;   // long tiles first (z is slowest dim)
  const int tid = threadIdx.x;
  const int wid = tid >> 6, lane = tid & 63;
  const int quad = lane >> 4, c16 = lane & 15;
  const size_t tokbase = (size_t)b * SEQ;
  const int q0 = t * 64;
  const int nkv = t + 1;

  // Q fragments (B-operand), scaled by 0.125 * log2(e)
  const unsigned short* qp = QKV + (tokbase + q0 + wid * 16 + c16) * 3072 + h * 64;
  bf16x8 qf[2];
#pragma unroll
  for (int ks = 0; ks < 2; ++ks) {
    u16x8 u = *(const u16x8*)(qp + ks * 32 + quad * 8);
    bf16x8 tq;
#pragma unroll
    for (int j = 0; j < 8; j++) tq[j] = (short)f2bf(0.1803368801f * bf2f(u[j]));
    qf[ks] = tq;
  }

  const unsigned short* kbase = QKV + tokbase * 3072 + 1024 + h * 64;
  const unsigned short* vbase = QKV + tokbase * 3072 + 2048 + h * 64;
  const int vkv = (tid >> 4) * 4;   // V stager: 4 kv rows
  const int vd = (tid & 15) * 4;    //           4 d cols

  f32x4 o[4];
  float lacc = 0.f;
#pragma unroll
  for (int nt = 0; nt < 4; nt++) o[nt] = f32x4{0.f, 0.f, 0.f, 0.f};
  unsigned short* PtW = sh.Pt[wid];
  const int pt_sub = (quad & 1) * 4;
  const int pt_c8h = quad >> 1;

  // ---- prologue: stage Kt[0]; load V(0) regs; write Vt[0] (pre-barrier)
  stage_glds<64, 4>(kbase, 3072, sh.Kt[0], wid, lane);
  u16x4 vr[4];
#pragma unroll
  for (int i = 0; i < 4; i++)
    vr[i] = *(const u16x4*)(vbase + (size_t)(vkv + i) * 3072 + vd);
#pragma unroll
  for (int dd = 0; dd < 4; ++dd) {   // compiler inserts vmcnt wait on vr here
    uint2 w;
    w.x = (unsigned int)vr[0][dd] | ((unsigned int)vr[1][dd] << 16);
    w.y = (unsigned int)vr[2][dd] | ((unsigned int)vr[3][dd] << 16);
    *(uint2*)&sh.Vt[0][vt_idx(vd + dd, vkv)] = w;
  }

  for (int kt = 0; kt < nkv; ++kt) {
    const int buf = kt & 1;
    // ONE barrier: publishes Vt[buf] writes (prev iter / prologue), drains
    // Kt[buf] glds (syncthreads waits vmcnt 0), frees Vt[buf^1]+Kt[buf^1].
    __syncthreads();

    const bool pf = (kt + 1 < nkv);
    if (pf) {   // issue next tile's K glds + V reg loads (fly over compute)
      const size_t nofs = (size_t)(kt + 1) * 64;
      stage_glds<64, 4>(kbase + nofs * 3072, 3072, sh.Kt[buf ^ 1], wid, lane);
#pragma unroll
      for (int i = 0; i < 4; i++)
        vr[i] = *(const u16x4*)(vbase + (nofs + vkv + i) * 3072 + vd);
    }

    // ---- S^T = K (Q*scale*log2e)^T - 16 : lane holds (kv=nt*16+quad*4+r, q=c16) ----
    const unsigned short* KtB = sh.Kt[buf];
    f32x4 st[4];
    __builtin_amdgcn_s_setprio(1);   // T5
#pragma unroll
    for (int nt = 0; nt < 4; ++nt) {
      f32x4 a = f32x4{-16.f, -16.f, -16.f, -16.f};
      a = MFMA16(frag_ld(KtB, nt * 16 + c16, quad), qf[0], a);
      a = MFMA16(frag_ld(KtB, nt * 16 + c16, 4 + quad), qf[1], a);
      st[nt] = a;
    }
    __builtin_amdgcn_s_setprio(0);
    if (kt == nkv - 1) {   // diagonal kv-tile
      const int kv0 = kt * 64;
      const int qg = q0 + wid * 16 + c16;
#pragma unroll
      for (int nt = 0; nt < 4; nt++)
#pragma unroll
        for (int r = 0; r < 4; r++) {
          int kg = kv0 + nt * 16 + quad * 4 + r;
          if (kg > qg) st[nt][r] = -1e30f;
        }
    }

    // ---- p = exp2(s); v_perm trunc-pack; XOR-chunk Pt writes ----
#pragma unroll
    for (int nt = 0; nt < 4; nt++) {
      float p0 = __builtin_amdgcn_exp2f(st[nt][0]);
      float p1 = __builtin_amdgcn_exp2f(st[nt][1]);
      float p2 = __builtin_amdgcn_exp2f(st[nt][2]);
      float p3 = __builtin_amdgcn_exp2f(st[nt][3]);
      lacc += (p0 + p1) + (p2 + p3);
      uint2 w;
      w.x = pkbf_trunc(p1, p0);
      w.y = pkbf_trunc(p3, p2);
      const int c8w = 2 * nt + pt_c8h;
      const int slot = c16 * 8 + (c8w ^ (c16 & 7));
      *(uint2*)&PtW[slot * 8 + pt_sub] = w;
    }

    if (pf) {   // write NEXT tile's V into the other Vt buffer (no barrier
                // needed before PV: PV reads Vt[buf], writes go to Vt[buf^1])
#pragma unroll
      for (int dd = 0; dd < 4; ++dd) {   // compiler vmcnt-waits on vr
        uint2 w;
        w.x = (unsigned int)vr[0][dd] | ((unsigned int)vr[1][dd] << 16);
        w.y = (unsigned int)vr[2][dd] | ((unsigned int)vr[3][dd] << 16);
        *(uint2*)&sh.Vt[buf ^ 1][vt_idx(vd + dd, vkv)] = w;
      }
    }

    // ---- O^T += V^T P^T (wave-private Pt; lgkmcnt-ordered, no barrier) ----
    const unsigned short* VtB = sh.Vt[buf];
    __builtin_amdgcn_s_setprio(1);   // T5
#pragma unroll
    for (int ks = 0; ks < 2; ++ks) {
      bf16x8 pfrag = frag_ld(PtW, c16, ks * 4 + quad);
#pragma unroll
      for (int nt2 = 0; nt2 < 4; ++nt2) {
        bf16x8 vf = *(const bf16x8*)&VtB[vt_idx(nt2 * 16 + c16, ks * 32 + quad * 8)];
        o[nt2] = MFMA16(vf, pfrag, o[nt2]);
      }
    }
    __builtin_amdgcn_s_setprio(0);
  }

  // ---- epilogue: l across quads (2 shuffles); packed dwordx2 stores ----
  lacc += __shfl_xor(lacc, 16);
  lacc += __shfl_xor(lacc, 32);
  const float linv = 1.f / lacc;
  const size_t row = tokbase + q0 + wid * 16 + c16;
#pragma unroll
  for (int nt2 = 0; nt2 < 4; nt2++) {
    uint2 w;
    w.x = (unsigned int)f2bf(o[nt2][0] * linv) | ((unsigned int)f2bf(o[nt2][1] * linv) << 16);
    w.y = (unsigned int)f2bf(o[nt2][2] * linv) | ((unsigned int)f2bf(o[nt2][3] * linv) << 16);
    *(uint2*)&Oa[row * 1024 + h * 64 + nt2 * 16 + quad * 4] = w;
  }
}

// =====================================================================
// Round-2 fallback GEMM (fp32 staging) — used only if ws_size < 40 MB.
// =====================================================================
template <int BM, int BN, int LDC, bool AF32, bool CF32>
__global__ __launch_bounds__(256) void gemm_bt(
    const void* __restrict__ Av, const float* __restrict__ W0, const float* __restrict__ W1,
    const float* __restrict__ W2, void* __restrict__ Cv) {
  constexpr int K = 1024;
  constexpr int LDS_LD = 72;
  constexpr int MI = BM / 32, NI = BN / 32;
  __shared__ __align__(16) unsigned short As[BM][LDS_LD];
  __shared__ __align__(16) unsigned short Bs[BN][LDS_LD];
  const int tid = threadIdx.x, wid = tid >> 6, lane = tid & 63;
  const int quad = lane >> 4, c16 = lane & 15;
  const int wrow = wid >> 1, wcol = wid & 1;
  const float* W = (blockIdx.z == 0) ? W0 : (blockIdx.z == 1 ? W1 : W2);
  const int m0 = blockIdx.y * BM, n0 = blockIdx.x * BN, cofs = blockIdx.z * 1024;
  f32x4 acc[MI][NI];
#pragma unroll
  for (int i = 0; i < MI; i++)
#pragma unroll
    for (int j = 0; j < NI; j++) acc[i][j] = f32x4{0.f, 0.f, 0.f, 0.f};
  for (int kb = 0; kb < K; kb += 64) {
    __syncthreads();
#pragma unroll
    for (int c = tid; c < BM * 8; c += 256) {
      int row = c >> 3, c8 = c & 7;
      if constexpr (AF32)
        *(u16x8*)&As[row][c8 * 8] = cvt8((const float*)Av + (size_t)(m0 + row) * K + kb + c8 * 8);
      else
        *(u16x8*)&As[row][c8 * 8] = *(const u16x8*)((const unsigned short*)Av + (size_t)(m0 + row) * K + kb + c8 * 8);
    }
#pragma unroll
    for (int c = tid; c < BN * 8; c += 256) {
      int row = c >> 3, c8 = c & 7;
      *(u16x8*)&Bs[row][c8 * 8] = cvt8(W + (size_t)(n0 + row) * K + kb + c8 * 8);
    }
    __syncthreads();
#pragma unroll
    for (int ks = 0; ks < 2; ++ks) {
      bf16x8 af[MI], bfr[NI];
#pragma unroll
      for (int i = 0; i < MI; i++)
        af[i] = *(const bf16x8*)&As[wrow * (BM / 2) + i * 16 + c16][ks * 32 + quad * 8];
#pragma unroll
      for (int j = 0; j < NI; j++)
        bfr[j] = *(const bf16x8*)&Bs[wcol * (BN / 2) + j * 16 + c16][ks * 32 + quad * 8];
#pragma unroll
      for (int i = 0; i < MI; i++)
#pragma unroll
        for (int j = 0; j < NI; j++) acc[i][j] = MFMA16(af[i], bfr[j], acc[i][j]);
    }
  }
#pragma unroll
  for (int i = 0; i < MI; i++)
#pragma unroll
    for (int j = 0; j < NI; j++) {
      int row = m0 + wrow * (BM / 2) + i * 16 + quad * 4;
      int col = n0 + wcol * (BN / 2) + j * 16 + c16 + cofs;
#pragma unroll
      for (int r = 0; r < 4; r++) {
        if constexpr (CF32) ((float*)Cv)[(size_t)(row + r) * LDC + col] = acc[i][j][r];
        else ((unsigned short*)Cv)[(size_t)(row + r) * LDC + col] = f2bf(acc[i][j][r]);
      }
    }
}

// =====================================================================
extern "C" void kernel_launch(void* const* d_in, const int* in_sizes, int n_in,
                              void* d_out, int out_size, void* d_ws, size_t ws_size,
                              hipStream_t stream) {
  const float* x = (const float*)d_in[0];
  const float* Wq = (const float*)d_in[2];
  const float* Wk = (const float*)d_in[3];
  const float* Wv = (const float*)d_in[4];
  const float* Wo = (const float*)d_in[5];
  float* out = (float*)d_out;

  unsigned short* QKV = (unsigned short*)d_ws;                 // [4096][3072] bf16 (24MB)
  unsigned short* Wb = QKV + (size_t)NTOK * 3072;              // 4 x [1024][1024] bf16 (8MB)
  unsigned short* Xb = Wb + (size_t)4 * 1024 * 1024;           // [4096][1024] bf16 (8MB), == AT
  unsigned short* AT = Xb;

  if (ws_size >= (size_t)40 * 1024 * 1024) {
    cvt_all<<<dim3(256, 5), 256, 0, stream>>>(x, Wq, Wk, Wv, Wo, Xb, Wb);
    // fused QKV projection: 256x192 8-phase, single barrier/phase
    gemm_8ph_w192<<<dim3(256), 512, 0, stream>>>(Xb, Wb, QKV);
    // flash attention v14: single-barrier pipeline, Vt double-buffer
    attn_kernel<<<dim3(NH, 2, 32), 256, 0, stream>>>(QKV, AT);
    // output projection: 2-phase dbuf counted-vmcnt (NEW this round)
    gemm_op_2ph<<<dim3(512), 256, 0, stream>>>(
        AT, Wb + (size_t)3 * 1024 * 1024, out);
  } else {
    unsigned short* QKV2 = (unsigned short*)d_ws;
    unsigned short* AT2 = QKV2 + (size_t)NTOK * 3072;
    gemm_bt<128, 128, 3072, true, false><<<dim3(8, 32, 3), 256, 0, stream>>>(x, Wq, Wk, Wv, QKV2);
    attn_kernel<<<dim3(NH, 2, 32), 256, 0, stream>>>(QKV2, AT2);
    gemm_bt<64, 64, 1024, false, true><<<dim3(16, 64, 1), 256, 0, stream>>>(AT2, Wo, Wo, Wo, out);
  }
}

// Round 10
// 173.853 us; speedup vs baseline: 1.0018x; 1.0018x over previous
//
#include <hip/hip_runtime.h>
#include <hip/hip_bf16.h>

// ---- types ----
typedef short bf16x8 __attribute__((ext_vector_type(8)));          // 8 bf16 = 4 VGPRs (MFMA A/B frag)
typedef unsigned short u16x8 __attribute__((ext_vector_type(8)));
typedef unsigned short u16x4 __attribute__((ext_vector_type(4)));
typedef float f32x4 __attribute__((ext_vector_type(4)));           // MFMA C/D frag

typedef unsigned int __attribute__((address_space(1))) gu32;       // global
typedef unsigned int __attribute__((address_space(3))) lu32;       // LDS

#define MFMA16(a, b, c) __builtin_amdgcn_mfma_f32_16x16x32_bf16((a), (b), (c), 0, 0, 0)

constexpr int SEQ = 2048;
constexpr int NH = 16;
constexpr int NTOK = 2 * SEQ;  // 4096

__device__ __forceinline__ float bf2f(unsigned short u) {
  union { unsigned int i; float f; } v; v.i = ((unsigned int)u) << 16; return v.f;
}
__device__ __forceinline__ unsigned short f2bf(float f) {
  __hip_bfloat16 h = __float2bfloat16(f);   // RNE
  return __builtin_bit_cast(unsigned short, h);
}
// pack two fp32 -> bf16 pair by TRUNCATION via one v_perm_b32 (hi<<16 | lo)
__device__ __forceinline__ unsigned int pkbf_trunc(float hi, float lo) {
  return __builtin_amdgcn_perm(__builtin_bit_cast(unsigned int, hi),
                               __builtin_bit_cast(unsigned int, lo), 0x07060302u);
}
__device__ __forceinline__ u16x8 cvt8(const float* __restrict__ p) {
  f32x4 a = *(const f32x4*)p;
  f32x4 b = *(const f32x4*)(p + 4);
  u16x8 r;
#pragma unroll
  for (int j = 0; j < 4; j++) { r[j] = f2bf(a[j]); r[4 + j] = f2bf(b[j]); }
  return r;
}

// =====================================================================
// Convert pass v2: flat 1-D grid over all 8M elements (x 4M + weights
// 4x1M contiguous into Wb). r9 audit: old dim3(256,5) launch gave z=0
// (x, 4M elems) 4x the work of each weight slice -> 4/5 of the grid
// idled while z=0 ran 8 sweeps (13 µs, ~3.7 TB/s). Now 2048 blocks x
// 256 thr x 8 elems = exactly 2 iters/thread, perfectly balanced.
// 8-elem vectors never straddle the 1M boundaries (1M % 8 == 0).
// =====================================================================
__global__ __launch_bounds__(256) void cvt_all(
    const float* __restrict__ x, const float* __restrict__ wq, const float* __restrict__ wk,
    const float* __restrict__ wv, const float* __restrict__ wo,
    unsigned short* __restrict__ Xb, unsigned short* __restrict__ Wb) {
  const size_t XN = (size_t)NTOK * 1024;        // 4M
  const size_t TOT = XN + (size_t)4 * 1024 * 1024;  // 8M
  for (size_t i = ((size_t)blockIdx.x * 256 + threadIdx.x) * 8; i < TOT;
       i += (size_t)gridDim.x * 256 * 8) {
    if (i < XN) {
      *(u16x8*)(Xb + i) = cvt8(x + i);
    } else {
      const size_t j = i - XN;
      const int w = (int)(j >> 20);   // which 1M-elem weight
      const float* src = (w == 0) ? wq : (w == 1) ? wk : (w == 2) ? wv : wo;
      *(u16x8*)(Wb + j) = cvt8(src + (j & (((size_t)1 << 20) - 1)));
    }
  }
}

// =====================================================================
// Async global->LDS staging with XOR-chunk permutation (verified r3):
// 16B chunk (row, c8) -> slot row*8 + (c8 ^ (row&7)).
// =====================================================================
template <int ROWS, int NWAVE>
__device__ __forceinline__ void stage_glds(const unsigned short* __restrict__ gbase,
                                           int rstride,
                                           unsigned short* __restrict__ lds,
                                           int wid, int lane) {
  constexpr int ISS = ROWS * 8 / (NWAVE * 64);
#pragma unroll
  for (int t = 0; t < ISS; ++t) {
    const int slot = (wid * ISS + t) * 64 + lane;
    const int row = slot >> 3;
    const int c8 = (slot & 7) ^ (row & 7);
    const unsigned short* gp = gbase + (size_t)row * rstride + c8 * 8;
    unsigned short* lp = lds + (size_t)(wid * ISS + t) * 512;   // wave-uniform, 1 KiB/issue
    __builtin_amdgcn_global_load_lds((const gu32*)gp, (lu32*)lp, 16, 0, 0);
  }
}

__device__ __forceinline__ bf16x8 frag_ld(const unsigned short* __restrict__ lds, int row, int c8) {
  const int slot = row * 8 + (c8 ^ (row & 7));
  return *(const bf16x8*)(lds + slot * 8);
}

#define SBAR do { __builtin_amdgcn_sched_barrier(0); \
                  asm volatile("s_barrier" ::: "memory"); \
                  __builtin_amdgcn_sched_barrier(0); } while (0)

// =====================================================================
// m97-style bf16 GEMM, XCD-local grid — PROVEN for the OUTPUT
// projection (r8: part of the 172.8 µs best; r9's 2-phase rewrite was
// 1.3 µs WORSE -> reverted). At 2 blocks/CU the co-resident block
// already hides most stage latency. FROZEN.
// =====================================================================
template <int BM, int BN, int LDC, bool CF32>
__global__ __launch_bounds__(256) void gemm_lds(
    const unsigned short* __restrict__ A,   // [M][1024] bf16 row-major
    const unsigned short* __restrict__ B,   // [LDC][1024] bf16 (nn.Linear weight rows)
    void* __restrict__ Cv) {
  constexpr int K = 1024;
  constexpr int MI = BM / 32, NI = BN / 32;

  __shared__ __align__(16) unsigned short As[BM * 64];
  __shared__ __align__(16) unsigned short Bs[BN * 64];

  const int tid = threadIdx.x;
  const int wid = tid >> 6;
  const int lane = tid & 63;
  const int quad = lane >> 4;
  const int c16 = lane & 15;
  const int wrow = wid >> 1, wcol = wid & 1;

  const int m0 = blockIdx.x * BM;   // m fastest -> same-A blocks share an XCD
  const int n0 = blockIdx.y * BN;

  f32x4 acc[MI][NI];
#pragma unroll
  for (int i = 0; i < MI; i++)
#pragma unroll
    for (int j = 0; j < NI; j++) acc[i][j] = f32x4{0.f, 0.f, 0.f, 0.f};

  for (int kb = 0; kb < K; kb += 64) {
    __syncthreads();
    stage_glds<BM, 4>(A + (size_t)m0 * K + kb, K, As, wid, lane);
    stage_glds<BN, 4>(B + (size_t)n0 * K + kb, K, Bs, wid, lane);
    __syncthreads();
#pragma unroll
    for (int ks = 0; ks < 2; ++ks) {
      bf16x8 af[MI], bfr[NI];
#pragma unroll
      for (int i = 0; i < MI; i++)
        af[i] = frag_ld(As, wrow * (BM / 2) + i * 16 + c16, ks * 4 + quad);
#pragma unroll
      for (int j = 0; j < NI; j++)
        bfr[j] = frag_ld(Bs, wcol * (BN / 2) + j * 16 + c16, ks * 4 + quad);
#pragma unroll
      for (int i = 0; i < MI; i++)
#pragma unroll
        for (int j = 0; j < NI; j++) acc[i][j] = MFMA16(af[i], bfr[j], acc[i][j]);
    }
  }

#pragma unroll
  for (int i = 0; i < MI; i++) {
#pragma unroll
    for (int j = 0; j < NI; j++) {
      int row = m0 + wrow * (BM / 2) + i * 16 + quad * 4;
      int col = n0 + wcol * (BN / 2) + j * 16 + c16;
#pragma unroll
      for (int r = 0; r < 4; r++) {
        if constexpr (CF32) ((float*)Cv)[(size_t)(row + r) * LDC + col] = acc[i][j][r];
        else ((unsigned short*)Cv)[(size_t)(row + r) * LDC + col] = f2bf(acc[i][j][r]);
      }
    }
  }
}

// =====================================================================
// QKV projection: 256x192-tile 8-phase GEMM (T2+T3+T4+T5) — verified
// r5/r8 (256 blocks = 100% CU, one barrier/phase). vmcnt(3) at P4/P8.
// =====================================================================
__global__ __launch_bounds__(512) void gemm_8ph_w192(
    const unsigned short* __restrict__ A,   // [4096][1024] bf16
    const unsigned short* __restrict__ B,   // [3072][1024] bf16 (Wq|Wk|Wv rows)
    unsigned short* __restrict__ C) {       // [4096][3072] bf16
  constexpr int K = 1024;
  __shared__ __align__(16) unsigned short As[2][256 * 64];   // 32 KiB x2
  __shared__ __align__(16) unsigned short Bs[2][192 * 64];   // 24 KiB x2

  const int tid = threadIdx.x;
  const int wid = tid >> 6, lane = tid & 63;
  const int quad = lane >> 4, c16 = lane & 15;
  const int wr = wid >> 2;        // 0..1  -> 128 output rows
  const int wc = wid & 3;         // 0..3  -> 48 output cols

  const int bid = blockIdx.x;
  const int swz = (bid & 7) * 32 + (bid >> 3);
  const int m0 = (swz >> 4) * 256;
  const int n0 = (swz & 15) * 192;

  const unsigned short* Abase = A + (size_t)m0 * K;
  const unsigned short* Bbase = B + (size_t)n0 * K;

  f32x4 acc[8][3];
#pragma unroll
  for (int i = 0; i < 8; i++)
#pragma unroll
    for (int j = 0; j < 3; j++) acc[i][j] = f32x4{0.f, 0.f, 0.f, 0.f};

  bf16x8 af[4];
  bf16x8 bf0[3];
  bf16x8 bf1[3];

  auto lda4 = [&](const unsigned short* asb, int mo, int ks) {
#pragma unroll
    for (int mi = 0; mi < 4; mi++)
      af[mi] = frag_ld(asb, wr * 128 + (mo + mi) * 16 + c16, ks * 4 + quad);
  };
  auto ldb3 = [&](const unsigned short* bsb, bf16x8 (&bf)[3], int ks) {
#pragma unroll
    for (int ni = 0; ni < 3; ni++)
      bf[ni] = frag_ld(bsb, wc * 48 + ni * 16 + c16, ks * 4 + quad);
  };
  auto mm12 = [&](bf16x8 (&bf)[3], int mo) {
    __builtin_amdgcn_s_setprio(1);
#pragma unroll
    for (int mi = 0; mi < 4; mi++)
#pragma unroll
      for (int ni = 0; ni < 3; ni++)
        acc[mo + mi][ni] = MFMA16(af[mi], bf[ni], acc[mo + mi][ni]);
    __builtin_amdgcn_s_setprio(0);
  };

  // ---- prologue
  stage_glds<192, 8>(Bbase, K, Bs[0], wid, lane);
  stage_glds<128, 8>(Abase, K, As[0], wid, lane);
  stage_glds<128, 8>(Abase + (size_t)128 * K, K, As[0] + 8192, wid, lane);
  stage_glds<192, 8>(Bbase + 64, K, Bs[1], wid, lane);
  asm volatile("s_waitcnt vmcnt(3)" ::: "memory");   // tile 0 landed; B(1) in flight
  SBAR;

  for (int i = 0; i < 7; ++i) {
    const int t = 2 * i;
    const int kb1 = (t + 1) * 64, kb2 = (t + 2) * 64, kb3 = (t + 3) * 64;
    // P1
    lda4(As[0], 0, 0); ldb3(Bs[0], bf0, 0);
    stage_glds<128, 8>(Abase + kb1, K, As[1], wid, lane);
    mm12(bf0, 0); SBAR;
    // P2
    lda4(As[0], 0, 1); ldb3(Bs[0], bf1, 1);
    stage_glds<128, 8>(Abase + (size_t)128 * K + kb1, K, As[1] + 8192, wid, lane);
    mm12(bf1, 0); SBAR;
    // P3
    lda4(As[0], 4, 0);
    stage_glds<192, 8>(Bbase + kb2, K, Bs[0], wid, lane);
    mm12(bf0, 4); SBAR;
    // P4
    lda4(As[0], 4, 1);
    asm volatile("s_waitcnt vmcnt(3)" ::: "memory");   // t+1 landed; B(t+2) in flight
    mm12(bf1, 4); SBAR;
    // P5
    lda4(As[1], 0, 0); ldb3(Bs[1], bf0, 0);
    stage_glds<128, 8>(Abase + kb2, K, As[0], wid, lane);
    mm12(bf0, 0); SBAR;
    // P6
    lda4(As[1], 0, 1); ldb3(Bs[1], bf1, 1);
    stage_glds<128, 8>(Abase + (size_t)128 * K + kb2, K, As[0] + 8192, wid, lane);
    mm12(bf1, 0); SBAR;
    // P7
    lda4(As[1], 4, 0);
    stage_glds<192, 8>(Bbase + kb3, K, Bs[1], wid, lane);
    mm12(bf0, 4); SBAR;
    // P8
    lda4(As[1], 4, 1);
    asm volatile("s_waitcnt vmcnt(3)" ::: "memory");   // t+2 landed; B(t+3) in flight
    mm12(bf1, 4); SBAR;
  }

  // ---- final iteration: t=14 (buf0), t=15 (buf1); stage only A(15)
  {
    const int kb1 = 15 * 64;
    lda4(As[0], 0, 0); ldb3(Bs[0], bf0, 0);
    stage_glds<128, 8>(Abase + kb1, K, As[1], wid, lane);
    mm12(bf0, 0); SBAR;
    lda4(As[0], 0, 1); ldb3(Bs[0], bf1, 1);
    stage_glds<128, 8>(Abase + (size_t)128 * K + kb1, K, As[1] + 8192, wid, lane);
    mm12(bf1, 0); SBAR;
    lda4(As[0], 4, 0);
    mm12(bf0, 4); SBAR;
    lda4(As[0], 4, 1);
    asm volatile("s_waitcnt vmcnt(0)" ::: "memory");   // drain: A(15) covered
    mm12(bf1, 4); SBAR;
    lda4(As[1], 0, 0); ldb3(Bs[1], bf0, 0);
    mm12(bf0, 0); SBAR;
    lda4(As[1], 0, 1); ldb3(Bs[1], bf1, 1);
    mm12(bf1, 0); SBAR;
    lda4(As[1], 4, 0);
    mm12(bf0, 4); SBAR;
    lda4(As[1], 4, 1);
    mm12(bf1, 4);
  }

#pragma unroll
  for (int mi = 0; mi < 8; mi++) {
#pragma unroll
    for (int ni = 0; ni < 3; ni++) {
      const int row = m0 + wr * 128 + mi * 16 + quad * 4;
      const int col = n0 + wc * 48 + ni * 16 + c16;
#pragma unroll
      for (int r = 0; r < 4; r++)
        C[(size_t)(row + r) * 3072 + col] = f2bf(acc[mi][ni][r]);
    }
  }
}

// =====================================================================
// Flash attention v14 (causal) — single-barrier pipeline, Vt dbuf
// (verified r7/r8: 41.3 µs). At its structural floor for this
// decomposition (r8 bank-audit: all LDS accesses balanced). FROZEN.
// =====================================================================
__device__ __forceinline__ int vt_idx(int d, int kv) {
  int ck = kv >> 3;
  int s = ((d >> 3) ^ d) & 7;
  return d * 64 + ((ck ^ s) << 3) + (kv & 7);
}

struct AttnShared {
  unsigned short Kt[2][64 * 64];   // XOR-chunk swizzled K rows (8 KB x2)
  unsigned short Vt[2][64 * 64];   // vt_idx-swizzled V^T (8 KB x2)
  unsigned short Pt[4][16 * 64];   // per-wave 16x64 XOR-chunk P^T tile (8 KB)
};

__global__ __launch_bounds__(256) void attn_kernel(
    const unsigned short* __restrict__ QKV,   // [NTOK][3072]: Q | K | V (bf16)
    unsigned short* __restrict__ Oa) {        // [NTOK][1024] bf16
  __shared__ AttnShared sh;
  const int h = blockIdx.x;
  const int b = blockIdx.y;
  const int t = 31 - blockIdx.z;   // long tiles first (z is slowest dim)
  const int tid = threadIdx.x;
  const int wid = tid >> 6, lane = tid & 63;
  const int quad = lane >> 4, c16 = lane & 15;
  const size_t tokbase = (size_t)b * SEQ;
  const int q0 = t * 64;
  const int nkv = t + 1;

  // Q fragments (B-operand), scaled by 0.125 * log2(e)
  const unsigned short* qp = QKV + (tokbase + q0 + wid * 16 + c16) * 3072 + h * 64;
  bf16x8 qf[2];
#pragma unroll
  for (int ks = 0; ks < 2; ++ks) {
    u16x8 u = *(const u16x8*)(qp + ks * 32 + quad * 8);
    bf16x8 tq;
#pragma unroll
    for (int j = 0; j < 8; j++) tq[j] = (short)f2bf(0.1803368801f * bf2f(u[j]));
    qf[ks] = tq;
  }

  const unsigned short* kbase = QKV + tokbase * 3072 + 1024 + h * 64;
  const unsigned short* vbase = QKV + tokbase * 3072 + 2048 + h * 64;
  const int vkv = (tid >> 4) * 4;   // V stager: 4 kv rows
  const int vd = (tid & 15) * 4;    //           4 d cols

  f32x4 o[4];
  float lacc = 0.f;
#pragma unroll
  for (int nt = 0; nt < 4; nt++) o[nt] = f32x4{0.f, 0.f, 0.f, 0.f};
  unsigned short* PtW = sh.Pt[wid];
  const int pt_sub = (quad & 1) * 4;
  const int pt_c8h = quad >> 1;

  // ---- prologue: stage Kt[0]; load V(0) regs; write Vt[0] (pre-barrier)
  stage_glds<64, 4>(kbase, 3072, sh.Kt[0], wid, lane);
  u16x4 vr[4];
#pragma unroll
  for (int i = 0; i < 4; i++)
    vr[i] = *(const u16x4*)(vbase + (size_t)(vkv + i) * 3072 + vd);
#pragma unroll
  for (int dd = 0; dd < 4; ++dd) {   // compiler inserts vmcnt wait on vr here
    uint2 w;
    w.x = (unsigned int)vr[0][dd] | ((unsigned int)vr[1][dd] << 16);
    w.y = (unsigned int)vr[2][dd] | ((unsigned int)vr[3][dd] << 16);
    *(uint2*)&sh.Vt[0][vt_idx(vd + dd, vkv)] = w;
  }

  for (int kt = 0; kt < nkv; ++kt) {
    const int buf = kt & 1;
    // ONE barrier: publishes Vt[buf] writes (prev iter / prologue), drains
    // Kt[buf] glds (syncthreads waits vmcnt 0), frees Vt[buf^1]+Kt[buf^1].
    __syncthreads();

    const bool pf = (kt + 1 < nkv);
    if (pf) {   // issue next tile's K glds + V reg loads (fly over compute)
      const size_t nofs = (size_t)(kt + 1) * 64;
      stage_glds<64, 4>(kbase + nofs * 3072, 3072, sh.Kt[buf ^ 1], wid, lane);
#pragma unroll
      for (int i = 0; i < 4; i++)
        vr[i] = *(const u16x4*)(vbase + (nofs + vkv + i) * 3072 + vd);
    }

    // ---- S^T = K (Q*scale*log2e)^T - 16 : lane holds (kv=nt*16+quad*4+r, q=c16) ----
    const unsigned short* KtB = sh.Kt[buf];
    f32x4 st[4];
    __builtin_amdgcn_s_setprio(1);   // T5
#pragma unroll
    for (int nt = 0; nt < 4; ++nt) {
      f32x4 a = f32x4{-16.f, -16.f, -16.f, -16.f};
      a = MFMA16(frag_ld(KtB, nt * 16 + c16, quad), qf[0], a);
      a = MFMA16(frag_ld(KtB, nt * 16 + c16, 4 + quad), qf[1], a);
      st[nt] = a;
    }
    __builtin_amdgcn_s_setprio(0);
    if (kt == nkv - 1) {   // diagonal kv-tile
      const int kv0 = kt * 64;
      const int qg = q0 + wid * 16 + c16;
#pragma unroll
      for (int nt = 0; nt < 4; nt++)
#pragma unroll
        for (int r = 0; r < 4; r++) {
          int kg = kv0 + nt * 16 + quad * 4 + r;
          if (kg > qg) st[nt][r] = -1e30f;
        }
    }

    // ---- p = exp2(s); v_perm trunc-pack; XOR-chunk Pt writes ----
#pragma unroll
    for (int nt = 0; nt < 4; nt++) {
      float p0 = __builtin_amdgcn_exp2f(st[nt][0]);
      float p1 = __builtin_amdgcn_exp2f(st[nt][1]);
      float p2 = __builtin_amdgcn_exp2f(st[nt][2]);
      float p3 = __builtin_amdgcn_exp2f(st[nt][3]);
      lacc += (p0 + p1) + (p2 + p3);
      uint2 w;
      w.x = pkbf_trunc(p1, p0);
      w.y = pkbf_trunc(p3, p2);
      const int c8w = 2 * nt + pt_c8h;
      const int slot = c16 * 8 + (c8w ^ (c16 & 7));
      *(uint2*)&PtW[slot * 8 + pt_sub] = w;
    }

    if (pf) {   // write NEXT tile's V into the other Vt buffer (no barrier
                // needed before PV: PV reads Vt[buf], writes go to Vt[buf^1])
#pragma unroll
      for (int dd = 0; dd < 4; ++dd) {   // compiler vmcnt-waits on vr
        uint2 w;
        w.x = (unsigned int)vr[0][dd] | ((unsigned int)vr[1][dd] << 16);
        w.y = (unsigned int)vr[2][dd] | ((unsigned int)vr[3][dd] << 16);
        *(uint2*)&sh.Vt[buf ^ 1][vt_idx(vd + dd, vkv)] = w;
      }
    }

    // ---- O^T += V^T P^T (wave-private Pt; lgkmcnt-ordered, no barrier) ----
    const unsigned short* VtB = sh.Vt[buf];
    __builtin_amdgcn_s_setprio(1);   // T5
#pragma unroll
    for (int ks = 0; ks < 2; ++ks) {
      bf16x8 pfrag = frag_ld(PtW, c16, ks * 4 + quad);
#pragma unroll
      for (int nt2 = 0; nt2 < 4; ++nt2) {
        bf16x8 vf = *(const bf16x8*)&VtB[vt_idx(nt2 * 16 + c16, ks * 32 + quad * 8)];
        o[nt2] = MFMA16(vf, pfrag, o[nt2]);
      }
    }
    __builtin_amdgcn_s_setprio(0);
  }

  // ---- epilogue: l across quads (2 shuffles); packed dwordx2 stores ----
  lacc += __shfl_xor(lacc, 16);
  lacc += __shfl_xor(lacc, 32);
  const float linv = 1.f / lacc;
  const size_t row = tokbase + q0 + wid * 16 + c16;
#pragma unroll
  for (int nt2 = 0; nt2 < 4; nt2++) {
    uint2 w;
    w.x = (unsigned int)f2bf(o[nt2][0] * linv) | ((unsigned int)f2bf(o[nt2][1] * linv) << 16);
    w.y = (unsigned int)f2bf(o[nt2][2] * linv) | ((unsigned int)f2bf(o[nt2][3] * linv) << 16);
    *(uint2*)&Oa[row * 1024 + h * 64 + nt2 * 16 + quad * 4] = w;
  }
}

// =====================================================================
// Round-2 fallback GEMM (fp32 staging) — used only if ws_size < 40 MB.
// =====================================================================
template <int BM, int BN, int LDC, bool AF32, bool CF32>
__global__ __launch_bounds__(256) void gemm_bt(
    const void* __restrict__ Av, const float* __restrict__ W0, const float* __restrict__ W1,
    const float* __restrict__ W2, void* __restrict__ Cv) {
  constexpr int K = 1024;
  constexpr int LDS_LD = 72;
  constexpr int MI = BM / 32, NI = BN / 32;
  __shared__ __align__(16) unsigned short As[BM][LDS_LD];
  __shared__ __align__(16) unsigned short Bs[BN][LDS_LD];
  const int tid = threadIdx.x, wid = tid >> 6, lane = tid & 63;
  const int quad = lane >> 4, c16 = lane & 15;
  const int wrow = wid >> 1, wcol = wid & 1;
  const float* W = (blockIdx.z == 0) ? W0 : (blockIdx.z == 1 ? W1 : W2);
  const int m0 = blockIdx.y * BM, n0 = blockIdx.x * BN, cofs = blockIdx.z * 1024;
  f32x4 acc[MI][NI];
#pragma unroll
  for (int i = 0; i < MI; i++)
#pragma unroll
    for (int j = 0; j < NI; j++) acc[i][j] = f32x4{0.f, 0.f, 0.f, 0.f};
  for (int kb = 0; kb < K; kb += 64) {
    __syncthreads();
#pragma unroll
    for (int c = tid; c < BM * 8; c += 256) {
      int row = c >> 3, c8 = c & 7;
      if constexpr (AF32)
        *(u16x8*)&As[row][c8 * 8] = cvt8((const float*)Av + (size_t)(m0 + row) * K + kb + c8 * 8);
      else
        *(u16x8*)&As[row][c8 * 8] = *(const u16x8*)((const unsigned short*)Av + (size_t)(m0 + row) * K + kb + c8 * 8);
    }
#pragma unroll
    for (int c = tid; c < BN * 8; c += 256) {
      int row = c >> 3, c8 = c & 7;
      *(u16x8*)&Bs[row][c8 * 8] = cvt8(W + (size_t)(n0 + row) * K + kb + c8 * 8);
    }
    __syncthreads();
#pragma unroll
    for (int ks = 0; ks < 2; ++ks) {
      bf16x8 af[MI], bfr[NI];
#pragma unroll
      for (int i = 0; i < MI; i++)
        af[i] = *(const bf16x8*)&As[wrow * (BM / 2) + i * 16 + c16][ks * 32 + quad * 8];
#pragma unroll
      for (int j = 0; j < NI; j++)
        bfr[j] = *(const bf16x8*)&Bs[wcol * (BN / 2) + j * 16 + c16][ks * 32 + quad * 8];
#pragma unroll
      for (int i = 0; i < MI; i++)
#pragma unroll
        for (int j = 0; j < NI; j++) acc[i][j] = MFMA16(af[i], bfr[j], acc[i][j]);
    }
  }
#pragma unroll
  for (int i = 0; i < MI; i++)
#pragma unroll
    for (int j = 0; j < NI; j++) {
      int row = m0 + wrow * (BM / 2) + i * 16 + quad * 4;
      int col = n0 + wcol * (BN / 2) + j * 16 + c16 + cofs;
#pragma unroll
      for (int r = 0; r < 4; r++) {
        if constexpr (CF32) ((float*)Cv)[(size_t)(row + r) * LDC + col] = acc[i][j][r];
        else ((unsigned short*)Cv)[(size_t)(row + r) * LDC + col] = f2bf(acc[i][j][r]);
      }
    }
}

// =====================================================================
extern "C" void kernel_launch(void* const* d_in, const int* in_sizes, int n_in,
                              void* d_out, int out_size, void* d_ws, size_t ws_size,
                              hipStream_t stream) {
  const float* x = (const float*)d_in[0];
  const float* Wq = (const float*)d_in[2];
  const float* Wk = (const float*)d_in[3];
  const float* Wv = (const float*)d_in[4];
  const float* Wo = (const float*)d_in[5];
  float* out = (float*)d_out;

  unsigned short* QKV = (unsigned short*)d_ws;                 // [4096][3072] bf16 (24MB)
  unsigned short* Wb = QKV + (size_t)NTOK * 3072;              // 4 x [1024][1024] bf16 (8MB)
  unsigned short* Xb = Wb + (size_t)4 * 1024 * 1024;           // [4096][1024] bf16 (8MB), == AT
  unsigned short* AT = Xb;

  if (ws_size >= (size_t)40 * 1024 * 1024) {
    // convert: flat balanced grid (2048 blocks, 2 iters/thread exactly)
    cvt_all<<<dim3(2048), 256, 0, stream>>>(x, Wq, Wk, Wv, Wo, Xb, Wb);
    // fused QKV projection: 256x192 8-phase, single barrier/phase
    gemm_8ph_w192<<<dim3(256), 512, 0, stream>>>(Xb, Wb, QKV);
    // flash attention v14: single-barrier pipeline, Vt double-buffer
    attn_kernel<<<dim3(NH, 2, 32), 256, 0, stream>>>(QKV, AT);
    // output projection: r8-proven gemm_lds 128x64 (r9 rewrite reverted)
    gemm_lds<128, 64, 1024, true><<<dim3(32, 16), 256, 0, stream>>>(
        AT, Wb + (size_t)3 * 1024 * 1024, out);
  } else {
    unsigned short* QKV2 = (unsigned short*)d_ws;
    unsigned short* AT2 = QKV2 + (size_t)NTOK * 3072;
    gemm_bt<128, 128, 3072, true, false><<<dim3(8, 32, 3), 256, 0, stream>>>(x, Wq, Wk, Wv, QKV2);
    attn_kernel<<<dim3(NH, 2, 32), 256, 0, stream>>>(QKV2, AT2);
    gemm_bt<64, 64, 1024, false, true><<<dim3(16, 64, 1), 256, 0, stream>>>(AT2, Wo, Wo, Wo, out);
  }
}

// Round 11
// 170.184 us; speedup vs baseline: 1.0234x; 1.0216x over previous
//
#include <hip/hip_runtime.h>
#include <hip/hip_bf16.h>

// ---- types ----
typedef short bf16x8 __attribute__((ext_vector_type(8)));          // 8 bf16 = 4 VGPRs (MFMA A/B frag)
typedef unsigned short u16x8 __attribute__((ext_vector_type(8)));
typedef unsigned short u16x4 __attribute__((ext_vector_type(4)));
typedef float f32x4 __attribute__((ext_vector_type(4)));           // MFMA C/D frag

typedef unsigned int __attribute__((address_space(1))) gu32;       // global
typedef unsigned int __attribute__((address_space(3))) lu32;       // LDS

#define MFMA16(a, b, c) __builtin_amdgcn_mfma_f32_16x16x32_bf16((a), (b), (c), 0, 0, 0)

constexpr int SEQ = 2048;
constexpr int NH = 16;
constexpr int NTOK = 2 * SEQ;  // 4096

__device__ __forceinline__ float bf2f(unsigned short u) {
  union { unsigned int i; float f; } v; v.i = ((unsigned int)u) << 16; return v.f;
}
__device__ __forceinline__ unsigned short f2bf(float f) {
  __hip_bfloat16 h = __float2bfloat16(f);   // RNE
  return __builtin_bit_cast(unsigned short, h);
}
// pack two fp32 -> bf16 pair by TRUNCATION via one v_perm_b32 (hi<<16 | lo)
__device__ __forceinline__ unsigned int pkbf_trunc(float hi, float lo) {
  return __builtin_amdgcn_perm(__builtin_bit_cast(unsigned int, hi),
                               __builtin_bit_cast(unsigned int, lo), 0x07060302u);
}
__device__ __forceinline__ u16x8 cvt8(const float* __restrict__ p) {
  f32x4 a = *(const f32x4*)p;
  f32x4 b = *(const f32x4*)(p + 4);
  u16x8 r;
#pragma unroll
  for (int j = 0; j < 4; j++) { r[j] = f2bf(a[j]); r[4 + j] = f2bf(b[j]); }
  return r;
}

// =====================================================================
// Convert pass v2: flat balanced 1-D grid (r10; ~null vs v1 but
// mechanism sound — 2048 blocks x 2 iters/thread exactly).
// =====================================================================
__global__ __launch_bounds__(256) void cvt_all(
    const float* __restrict__ x, const float* __restrict__ wq, const float* __restrict__ wk,
    const float* __restrict__ wv, const float* __restrict__ wo,
    unsigned short* __restrict__ Xb, unsigned short* __restrict__ Wb) {
  const size_t XN = (size_t)NTOK * 1024;        // 4M
  const size_t TOT = XN + (size_t)4 * 1024 * 1024;  // 8M
  for (size_t i = ((size_t)blockIdx.x * 256 + threadIdx.x) * 8; i < TOT;
       i += (size_t)gridDim.x * 256 * 8) {
    if (i < XN) {
      *(u16x8*)(Xb + i) = cvt8(x + i);
    } else {
      const size_t j = i - XN;
      const int w = (int)(j >> 20);   // which 1M-elem weight
      const float* src = (w == 0) ? wq : (w == 1) ? wk : (w == 2) ? wv : wo;
      *(u16x8*)(Wb + j) = cvt8(src + (j & (((size_t)1 << 20) - 1)));
    }
  }
}

// =====================================================================
// Async global->LDS staging with XOR-chunk permutation (verified r3):
// 16B chunk (row, c8) -> slot row*8 + (c8 ^ (row&7)).
// =====================================================================
template <int ROWS, int NWAVE>
__device__ __forceinline__ void stage_glds(const unsigned short* __restrict__ gbase,
                                           int rstride,
                                           unsigned short* __restrict__ lds,
                                           int wid, int lane) {
  constexpr int ISS = ROWS * 8 / (NWAVE * 64);
#pragma unroll
  for (int t = 0; t < ISS; ++t) {
    const int slot = (wid * ISS + t) * 64 + lane;
    const int row = slot >> 3;
    const int c8 = (slot & 7) ^ (row & 7);
    const unsigned short* gp = gbase + (size_t)row * rstride + c8 * 8;
    unsigned short* lp = lds + (size_t)(wid * ISS + t) * 512;   // wave-uniform, 1 KiB/issue
    __builtin_amdgcn_global_load_lds((const gu32*)gp, (lu32*)lp, 16, 0, 0);
  }
}

__device__ __forceinline__ bf16x8 frag_ld(const unsigned short* __restrict__ lds, int row, int c8) {
  const int slot = row * 8 + (c8 ^ (row & 7));
  return *(const bf16x8*)(lds + slot * 8);
}

#define SBAR do { __builtin_amdgcn_sched_barrier(0); \
                  asm volatile("s_barrier" ::: "memory"); \
                  __builtin_amdgcn_sched_barrier(0); } while (0)

// =====================================================================
// m97-style bf16 GEMM, XCD-local grid — PROVEN for the OUTPUT
// projection (r8/r10: part of best config; r9's 2-phase rewrite was
// worse -> kept). FROZEN.
// =====================================================================
template <int BM, int BN, int LDC, bool CF32>
__global__ __launch_bounds__(256) void gemm_lds(
    const unsigned short* __restrict__ A,   // [M][1024] bf16 row-major
    const unsigned short* __restrict__ B,   // [LDC][1024] bf16 (nn.Linear weight rows)
    void* __restrict__ Cv) {
  constexpr int K = 1024;
  constexpr int MI = BM / 32, NI = BN / 32;

  __shared__ __align__(16) unsigned short As[BM * 64];
  __shared__ __align__(16) unsigned short Bs[BN * 64];

  const int tid = threadIdx.x;
  const int wid = tid >> 6;
  const int lane = tid & 63;
  const int quad = lane >> 4;
  const int c16 = lane & 15;
  const int wrow = wid >> 1, wcol = wid & 1;

  const int m0 = blockIdx.x * BM;   // m fastest -> same-A blocks share an XCD
  const int n0 = blockIdx.y * BN;

  f32x4 acc[MI][NI];
#pragma unroll
  for (int i = 0; i < MI; i++)
#pragma unroll
    for (int j = 0; j < NI; j++) acc[i][j] = f32x4{0.f, 0.f, 0.f, 0.f};

  for (int kb = 0; kb < K; kb += 64) {
    __syncthreads();
    stage_glds<BM, 4>(A + (size_t)m0 * K + kb, K, As, wid, lane);
    stage_glds<BN, 4>(B + (size_t)n0 * K + kb, K, Bs, wid, lane);
    __syncthreads();
#pragma unroll
    for (int ks = 0; ks < 2; ++ks) {
      bf16x8 af[MI], bfr[NI];
#pragma unroll
      for (int i = 0; i < MI; i++)
        af[i] = frag_ld(As, wrow * (BM / 2) + i * 16 + c16, ks * 4 + quad);
#pragma unroll
      for (int j = 0; j < NI; j++)
        bfr[j] = frag_ld(Bs, wcol * (BN / 2) + j * 16 + c16, ks * 4 + quad);
#pragma unroll
      for (int i = 0; i < MI; i++)
#pragma unroll
        for (int j = 0; j < NI; j++) acc[i][j] = MFMA16(af[i], bfr[j], acc[i][j]);
    }
  }

#pragma unroll
  for (int i = 0; i < MI; i++) {
#pragma unroll
    for (int j = 0; j < NI; j++) {
      int row = m0 + wrow * (BM / 2) + i * 16 + quad * 4;
      int col = n0 + wcol * (BN / 2) + j * 16 + c16;
#pragma unroll
      for (int r = 0; r < 4; r++) {
        if constexpr (CF32) ((float*)Cv)[(size_t)(row + r) * LDC + col] = acc[i][j][r];
        else ((unsigned short*)Cv)[(size_t)(row + r) * LDC + col] = f2bf(acc[i][j][r]);
      }
    }
  }
}

// =====================================================================
// QKV projection: 256x192-tile GEMM, r11: FOUR merged phases/iteration
// (24 MFMA each) instead of eight of 12. r10 analysis: ~1160 cyc/phase
// vs ~250-400 cyc of work -> per-phase fixed overhead (barrier sync +
// exposed ds_read->MFMA chain) dominates; halving phase count halves it.
// Same stage sites / wait counts as the verified 8-phase schedule:
//   P12: lda both ks + ldb both ks | stage A(t+1) h0+h1 | 24 MFMA | bar
//   P34: lda mo4                   | stage B(t+2); vmcnt(3) | 24 MFMA | bar
//   P56/P78 mirror on buf1. Per-wave issue ledger: enter 3 (B(t+1)) ->
//   P12 +4=7 -> P34 +3=10, vmcnt(3) retires B(t+1)+A(t+1) (read in
//   P56/P78), leaves B(t+2). Final pair drains vmcnt(0).
// =====================================================================
__global__ __launch_bounds__(512) void gemm_4ph_w192(
    const unsigned short* __restrict__ A,   // [4096][1024] bf16
    const unsigned short* __restrict__ B,   // [3072][1024] bf16 (Wq|Wk|Wv rows)
    unsigned short* __restrict__ C) {       // [4096][3072] bf16
  constexpr int K = 1024;
  __shared__ __align__(16) unsigned short As[2][256 * 64];   // 32 KiB x2
  __shared__ __align__(16) unsigned short Bs[2][192 * 64];   // 24 KiB x2

  const int tid = threadIdx.x;
  const int wid = tid >> 6, lane = tid & 63;
  const int quad = lane >> 4, c16 = lane & 15;
  const int wr = wid >> 2;        // 0..1  -> 128 output rows
  const int wc = wid & 3;         // 0..3  -> 48 output cols

  const int bid = blockIdx.x;
  const int swz = (bid & 7) * 32 + (bid >> 3);
  const int m0 = (swz >> 4) * 256;
  const int n0 = (swz & 15) * 192;

  const unsigned short* Abase = A + (size_t)m0 * K;
  const unsigned short* Bbase = B + (size_t)n0 * K;

  f32x4 acc[8][3];
#pragma unroll
  for (int i = 0; i < 8; i++)
#pragma unroll
    for (int j = 0; j < 3; j++) acc[i][j] = f32x4{0.f, 0.f, 0.f, 0.f};

  bf16x8 af[4][2];   // 4 m-rows x 2 ks (both K-slices live per phase)
  bf16x8 bf0[3];     // B frags ks=0
  bf16x8 bf1[3];     // B frags ks=1

  auto lda8 = [&](const unsigned short* asb, int mo) {
#pragma unroll
    for (int mi = 0; mi < 4; mi++)
#pragma unroll
      for (int ks = 0; ks < 2; ks++)
        af[mi][ks] = frag_ld(asb, wr * 128 + (mo + mi) * 16 + c16, ks * 4 + quad);
  };
  auto ldb6 = [&](const unsigned short* bsb) {
#pragma unroll
    for (int ni = 0; ni < 3; ni++) {
      bf0[ni] = frag_ld(bsb, wc * 48 + ni * 16 + c16, quad);
      bf1[ni] = frag_ld(bsb, wc * 48 + ni * 16 + c16, 4 + quad);
    }
  };
  auto mm24 = [&](int mo) {   // 24-MFMA merged phase
    __builtin_amdgcn_s_setprio(1);
#pragma unroll
    for (int mi = 0; mi < 4; mi++)
#pragma unroll
      for (int ni = 0; ni < 3; ni++) {
        acc[mo + mi][ni] = MFMA16(af[mi][0], bf0[ni], acc[mo + mi][ni]);
        acc[mo + mi][ni] = MFMA16(af[mi][1], bf1[ni], acc[mo + mi][ni]);
      }
    __builtin_amdgcn_s_setprio(0);
  };

  // ---- prologue: B(0):3, A(0):4, B(1):3 -> vmcnt(3) leaves B(1)
  stage_glds<192, 8>(Bbase, K, Bs[0], wid, lane);
  stage_glds<128, 8>(Abase, K, As[0], wid, lane);
  stage_glds<128, 8>(Abase + (size_t)128 * K, K, As[0] + 8192, wid, lane);
  stage_glds<192, 8>(Bbase + 64, K, Bs[1], wid, lane);
  asm volatile("s_waitcnt vmcnt(3)" ::: "memory");   // tile 0 landed
  SBAR;

  for (int i = 0; i < 7; ++i) {
    const int t = 2 * i;
    const int kb1 = (t + 1) * 64, kb2 = (t + 2) * 64, kb3 = (t + 3) * 64;
    // P12: tile t mo0 (both ks); stage A(t+1) h0+h1 -> As1
    lda8(As[0], 0); ldb6(Bs[0]);
    stage_glds<128, 8>(Abase + kb1, K, As[1], wid, lane);
    stage_glds<128, 8>(Abase + (size_t)128 * K + kb1, K, As[1] + 8192, wid, lane);
    mm24(0); SBAR;
    // P34: tile t mo4; stage B(t+2)->Bs0; vmcnt(3) -> t+1 landed
    lda8(As[0], 4);
    stage_glds<192, 8>(Bbase + kb2, K, Bs[0], wid, lane);
    asm volatile("s_waitcnt vmcnt(3)" ::: "memory");
    mm24(4); SBAR;
    // P56: tile t+1 mo0; stage A(t+2)->As0
    lda8(As[1], 0); ldb6(Bs[1]);
    stage_glds<128, 8>(Abase + kb2, K, As[0], wid, lane);
    stage_glds<128, 8>(Abase + (size_t)128 * K + kb2, K, As[0] + 8192, wid, lane);
    mm24(0); SBAR;
    // P78: tile t+1 mo4; stage B(t+3)->Bs1; vmcnt(3) -> t+2 landed
    lda8(As[1], 4);
    stage_glds<192, 8>(Bbase + kb3, K, Bs[1], wid, lane);
    asm volatile("s_waitcnt vmcnt(3)" ::: "memory");
    mm24(4); SBAR;
  }

  // ---- final pair: t=14 (buf0), t=15 (buf1); stage only A(15)
  {
    const int kb1 = 15 * 64;
    lda8(As[0], 0); ldb6(Bs[0]);
    stage_glds<128, 8>(Abase + kb1, K, As[1], wid, lane);
    stage_glds<128, 8>(Abase + (size_t)128 * K + kb1, K, As[1] + 8192, wid, lane);
    mm24(0); SBAR;
    lda8(As[0], 4);
    asm volatile("s_waitcnt vmcnt(0)" ::: "memory");   // drains A(15)+B(15)
    mm24(4); SBAR;
    lda8(As[1], 0); ldb6(Bs[1]);
    mm24(0); SBAR;
    lda8(As[1], 4);
    mm24(4);
  }

#pragma unroll
  for (int mi = 0; mi < 8; mi++) {
#pragma unroll
    for (int ni = 0; ni < 3; ni++) {
      const int row = m0 + wr * 128 + mi * 16 + quad * 4;
      const int col = n0 + wc * 48 + ni * 16 + c16;
#pragma unroll
      for (int r = 0; r < 4; r++)
        C[(size_t)(row + r) * 3072 + col] = f2bf(acc[mi][ni][r]);
    }
  }
}

// =====================================================================
// Flash attention v14 (causal) — single-barrier pipeline, Vt dbuf
// (verified r7-r10: 41.3-42.8 µs). Structural floor. FROZEN.
// =====================================================================
__device__ __forceinline__ int vt_idx(int d, int kv) {
  int ck = kv >> 3;
  int s = ((d >> 3) ^ d) & 7;
  return d * 64 + ((ck ^ s) << 3) + (kv & 7);
}

struct AttnShared {
  unsigned short Kt[2][64 * 64];   // XOR-chunk swizzled K rows (8 KB x2)
  unsigned short Vt[2][64 * 64];   // vt_idx-swizzled V^T (8 KB x2)
  unsigned short Pt[4][16 * 64];   // per-wave 16x64 XOR-chunk P^T tile (8 KB)
};

__global__ __launch_bounds__(256) void attn_kernel(
    const unsigned short* __restrict__ QKV,   // [NTOK][3072]: Q | K | V (bf16)
    unsigned short* __restrict__ Oa) {        // [NTOK][1024] bf16
  __shared__ AttnShared sh;
  const int h = blockIdx.x;
  const int b = blockIdx.y;
  const int t = 31 - blockIdx.z;   // long tiles first (z is slowest dim)
  const int tid = threadIdx.x;
  const int wid = tid >> 6, lane = tid & 63;
  const int quad = lane >> 4, c16 = lane & 15;
  const size_t tokbase = (size_t)b * SEQ;
  const int q0 = t * 64;
  const int nkv = t + 1;

  // Q fragments (B-operand), scaled by 0.125 * log2(e)
  const unsigned short* qp = QKV + (tokbase + q0 + wid * 16 + c16) * 3072 + h * 64;
  bf16x8 qf[2];
#pragma unroll
  for (int ks = 0; ks < 2; ++ks) {
    u16x8 u = *(const u16x8*)(qp + ks * 32 + quad * 8);
    bf16x8 tq;
#pragma unroll
    for (int j = 0; j < 8; j++) tq[j] = (short)f2bf(0.1803368801f * bf2f(u[j]));
    qf[ks] = tq;
  }

  const unsigned short* kbase = QKV + tokbase * 3072 + 1024 + h * 64;
  const unsigned short* vbase = QKV + tokbase * 3072 + 2048 + h * 64;
  const int vkv = (tid >> 4) * 4;   // V stager: 4 kv rows
  const int vd = (tid & 15) * 4;    //           4 d cols

  f32x4 o[4];
  float lacc = 0.f;
#pragma unroll
  for (int nt = 0; nt < 4; nt++) o[nt] = f32x4{0.f, 0.f, 0.f, 0.f};
  unsigned short* PtW = sh.Pt[wid];
  const int pt_sub = (quad & 1) * 4;
  const int pt_c8h = quad >> 1;

  // ---- prologue: stage Kt[0]; load V(0) regs; write Vt[0] (pre-barrier)
  stage_glds<64, 4>(kbase, 3072, sh.Kt[0], wid, lane);
  u16x4 vr[4];
#pragma unroll
  for (int i = 0; i < 4; i++)
    vr[i] = *(const u16x4*)(vbase + (size_t)(vkv + i) * 3072 + vd);
#pragma unroll
  for (int dd = 0; dd < 4; ++dd) {   // compiler inserts vmcnt wait on vr here
    uint2 w;
    w.x = (unsigned int)vr[0][dd] | ((unsigned int)vr[1][dd] << 16);
    w.y = (unsigned int)vr[2][dd] | ((unsigned int)vr[3][dd] << 16);
    *(uint2*)&sh.Vt[0][vt_idx(vd + dd, vkv)] = w;
  }

  for (int kt = 0; kt < nkv; ++kt) {
    const int buf = kt & 1;
    // ONE barrier: publishes Vt[buf] writes (prev iter / prologue), drains
    // Kt[buf] glds (syncthreads waits vmcnt 0), frees Vt[buf^1]+Kt[buf^1].
    __syncthreads();

    const bool pf = (kt + 1 < nkv);
    if (pf) {   // issue next tile's K glds + V reg loads (fly over compute)
      const size_t nofs = (size_t)(kt + 1) * 64;
      stage_glds<64, 4>(kbase + nofs * 3072, 3072, sh.Kt[buf ^ 1], wid, lane);
#pragma unroll
      for (int i = 0; i < 4; i++)
        vr[i] = *(const u16x4*)(vbase + (nofs + vkv + i) * 3072 + vd);
    }

    // ---- S^T = K (Q*scale*log2e)^T - 16 : lane holds (kv=nt*16+quad*4+r, q=c16) ----
    const unsigned short* KtB = sh.Kt[buf];
    f32x4 st[4];
    __builtin_amdgcn_s_setprio(1);   // T5
#pragma unroll
    for (int nt = 0; nt < 4; ++nt) {
      f32x4 a = f32x4{-16.f, -16.f, -16.f, -16.f};
      a = MFMA16(frag_ld(KtB, nt * 16 + c16, quad), qf[0], a);
      a = MFMA16(frag_ld(KtB, nt * 16 + c16, 4 + quad), qf[1], a);
      st[nt] = a;
    }
    __builtin_amdgcn_s_setprio(0);
    if (kt == nkv - 1) {   // diagonal kv-tile
      const int kv0 = kt * 64;
      const int qg = q0 + wid * 16 + c16;
#pragma unroll
      for (int nt = 0; nt < 4; nt++)
#pragma unroll
        for (int r = 0; r < 4; r++) {
          int kg = kv0 + nt * 16 + quad * 4 + r;
          if (kg > qg) st[nt][r] = -1e30f;
        }
    }

    // ---- p = exp2(s); v_perm trunc-pack; XOR-chunk Pt writes ----
#pragma unroll
    for (int nt = 0; nt < 4; nt++) {
      float p0 = __builtin_amdgcn_exp2f(st[nt][0]);
      float p1 = __builtin_amdgcn_exp2f(st[nt][1]);
      float p2 = __builtin_amdgcn_exp2f(st[nt][2]);
      float p3 = __builtin_amdgcn_exp2f(st[nt][3]);
      lacc += (p0 + p1) + (p2 + p3);
      uint2 w;
      w.x = pkbf_trunc(p1, p0);
      w.y = pkbf_trunc(p3, p2);
      const int c8w = 2 * nt + pt_c8h;
      const int slot = c16 * 8 + (c8w ^ (c16 & 7));
      *(uint2*)&PtW[slot * 8 + pt_sub] = w;
    }

    if (pf) {   // write NEXT tile's V into the other Vt buffer (no barrier
                // needed before PV: PV reads Vt[buf], writes go to Vt[buf^1])
#pragma unroll
      for (int dd = 0; dd < 4; ++dd) {   // compiler vmcnt-waits on vr
        uint2 w;
        w.x = (unsigned int)vr[0][dd] | ((unsigned int)vr[1][dd] << 16);
        w.y = (unsigned int)vr[2][dd] | ((unsigned int)vr[3][dd] << 16);
        *(uint2*)&sh.Vt[buf ^ 1][vt_idx(vd + dd, vkv)] = w;
      }
    }

    // ---- O^T += V^T P^T (wave-private Pt; lgkmcnt-ordered, no barrier) ----
    const unsigned short* VtB = sh.Vt[buf];
    __builtin_amdgcn_s_setprio(1);   // T5
#pragma unroll
    for (int ks = 0; ks < 2; ++ks) {
      bf16x8 pfrag = frag_ld(PtW, c16, ks * 4 + quad);
#pragma unroll
      for (int nt2 = 0; nt2 < 4; ++nt2) {
        bf16x8 vf = *(const bf16x8*)&VtB[vt_idx(nt2 * 16 + c16, ks * 32 + quad * 8)];
        o[nt2] = MFMA16(vf, pfrag, o[nt2]);
      }
    }
    __builtin_amdgcn_s_setprio(0);
  }

  // ---- epilogue: l across quads (2 shuffles); packed dwordx2 stores ----
  lacc += __shfl_xor(lacc, 16);
  lacc += __shfl_xor(lacc, 32);
  const float linv = 1.f / lacc;
  const size_t row = tokbase + q0 + wid * 16 + c16;
#pragma unroll
  for (int nt2 = 0; nt2 < 4; nt2++) {
    uint2 w;
    w.x = (unsigned int)f2bf(o[nt2][0] * linv) | ((unsigned int)f2bf(o[nt2][1] * linv) << 16);
    w.y = (unsigned int)f2bf(o[nt2][2] * linv) | ((unsigned int)f2bf(o[nt2][3] * linv) << 16);
    *(uint2*)&Oa[row * 1024 + h * 64 + nt2 * 16 + quad * 4] = w;
  }
}

// =====================================================================
// Round-2 fallback GEMM (fp32 staging) — used only if ws_size < 40 MB.
// =====================================================================
template <int BM, int BN, int LDC, bool AF32, bool CF32>
__global__ __launch_bounds__(256) void gemm_bt(
    const void* __restrict__ Av, const float* __restrict__ W0, const float* __restrict__ W1,
    const float* __restrict__ W2, void* __restrict__ Cv) {
  constexpr int K = 1024;
  constexpr int LDS_LD = 72;
  constexpr int MI = BM / 32, NI = BN / 32;
  __shared__ __align__(16) unsigned short As[BM][LDS_LD];
  __shared__ __align__(16) unsigned short Bs[BN][LDS_LD];
  const int tid = threadIdx.x, wid = tid >> 6, lane = tid & 63;
  const int quad = lane >> 4, c16 = lane & 15;
  const int wrow = wid >> 1, wcol = wid & 1;
  const float* W = (blockIdx.z == 0) ? W0 : (blockIdx.z == 1 ? W1 : W2);
  const int m0 = blockIdx.y * BM, n0 = blockIdx.x * BN, cofs = blockIdx.z * 1024;
  f32x4 acc[MI][NI];
#pragma unroll
  for (int i = 0; i < MI; i++)
#pragma unroll
    for (int j = 0; j < NI; j++) acc[i][j] = f32x4{0.f, 0.f, 0.f, 0.f};
  for (int kb = 0; kb < K; kb += 64) {
    __syncthreads();
#pragma unroll
    for (int c = tid; c < BM * 8; c += 256) {
      int row = c >> 3, c8 = c & 7;
      if constexpr (AF32)
        *(u16x8*)&As[row][c8 * 8] = cvt8((const float*)Av + (size_t)(m0 + row) * K + kb + c8 * 8);
      else
        *(u16x8*)&As[row][c8 * 8] = *(const u16x8*)((const unsigned short*)Av + (size_t)(m0 + row) * K + kb + c8 * 8);
    }
#pragma unroll
    for (int c = tid; c < BN * 8; c += 256) {
      int row = c >> 3, c8 = c & 7;
      *(u16x8*)&Bs[row][c8 * 8] = cvt8(W + (size_t)(n0 + row) * K + kb + c8 * 8);
    }
    __syncthreads();
#pragma unroll
    for (int ks = 0; ks < 2; ++ks) {
      bf16x8 af[MI], bfr[NI];
#pragma unroll
      for (int i = 0; i < MI; i++)
        af[i] = *(const bf16x8*)&As[wrow * (BM / 2) + i * 16 + c16][ks * 32 + quad * 8];
#pragma unroll
      for (int j = 0; j < NI; j++)
        bfr[j] = *(const bf16x8*)&Bs[wcol * (BN / 2) + j * 16 + c16][ks * 32 + quad * 8];
#pragma unroll
      for (int i = 0; i < MI; i++)
#pragma unroll
        for (int j = 0; j < NI; j++) acc[i][j] = MFMA16(af[i], bfr[j], acc[i][j]);
    }
  }
#pragma unroll
  for (int i = 0; i < MI; i++)
#pragma unroll
    for (int j = 0; j < NI; j++) {
      int row = m0 + wrow * (BM / 2) + i * 16 + quad * 4;
      int col = n0 + wcol * (BN / 2) + j * 16 + c16 + cofs;
#pragma unroll
      for (int r = 0; r < 4; r++) {
        if constexpr (CF32) ((float*)Cv)[(size_t)(row + r) * LDC + col] = acc[i][j][r];
        else ((unsigned short*)Cv)[(size_t)(row + r) * LDC + col] = f2bf(acc[i][j][r]);
      }
    }
}

// =====================================================================
extern "C" void kernel_launch(void* const* d_in, const int* in_sizes, int n_in,
                              void* d_out, int out_size, void* d_ws, size_t ws_size,
                              hipStream_t stream) {
  const float* x = (const float*)d_in[0];
  const float* Wq = (const float*)d_in[2];
  const float* Wk = (const float*)d_in[3];
  const float* Wv = (const float*)d_in[4];
  const float* Wo = (const float*)d_in[5];
  float* out = (float*)d_out;

  unsigned short* QKV = (unsigned short*)d_ws;                 // [4096][3072] bf16 (24MB)
  unsigned short* Wb = QKV + (size_t)NTOK * 3072;              // 4 x [1024][1024] bf16 (8MB)
  unsigned short* Xb = Wb + (size_t)4 * 1024 * 1024;           // [4096][1024] bf16 (8MB), == AT
  unsigned short* AT = Xb;

  if (ws_size >= (size_t)40 * 1024 * 1024) {
    // convert: flat balanced grid (2048 blocks, 2 iters/thread exactly)
    cvt_all<<<dim3(2048), 256, 0, stream>>>(x, Wq, Wk, Wv, Wo, Xb, Wb);
    // fused QKV projection: 256x192, FOUR merged phases (r11)
    gemm_4ph_w192<<<dim3(256), 512, 0, stream>>>(Xb, Wb, QKV);
    // flash attention v14: single-barrier pipeline, Vt double-buffer
    attn_kernel<<<dim3(NH, 2, 32), 256, 0, stream>>>(QKV, AT);
    // output projection: r8-proven gemm_lds 128x64
    gemm_lds<128, 64, 1024, true><<<dim3(32, 16), 256, 0, stream>>>(
        AT, Wb + (size_t)3 * 1024 * 1024, out);
  } else {
    unsigned short* QKV2 = (unsigned short*)d_ws;
    unsigned short* AT2 = QKV2 + (size_t)NTOK * 3072;
    gemm_bt<128, 128, 3072, true, false><<<dim3(8, 32, 3), 256, 0, stream>>>(x, Wq, Wk, Wv, QKV2);
    attn_kernel<<<dim3(NH, 2, 32), 256, 0, stream>>>(QKV2, AT2);
    gemm_bt<64, 64, 1024, false, true><<<dim3(16, 64, 1), 256, 0, stream>>>(AT2, Wo, Wo, Wo, out);
  }
}